// Round 12
// baseline (656.398 us; speedup 1.0000x reference)
//
#include <hip/hip_runtime.h>
#include <hip/hip_bf16.h>
#include <cstdint>
#include <cstddef>

typedef __attribute__((ext_vector_type(8))) short short8;
typedef __attribute__((ext_vector_type(4))) short short4v;
typedef __attribute__((ext_vector_type(4))) float f32x4;

__device__ __forceinline__ float bf2f(unsigned short u) {
  union { unsigned int i; float f; } v; v.i = ((unsigned int)u) << 16; return v.f;
}
__device__ __forceinline__ unsigned short f2bf(float f) {
  union { float f; unsigned int i; } v; v.f = f;
  unsigned int x = v.i;
  return (unsigned short)((x + 0x7fffu + ((x >> 16) & 1u)) >> 16);
}
__device__ __forceinline__ f32x4 mfma16(short8 a, short8 b, f32x4 c) {
  return __builtin_amdgcn_mfma_f32_16x16x32_bf16(a, b, c, 0, 0, 0);
}
// async global->LDS, 16B/lane. dst must be wave-uniform; HW writes dst + lane*16.
__device__ __forceinline__ void gload16(const void* src, void* dst) {
  __builtin_amdgcn_global_load_lds(
      (const __attribute__((address_space(1))) unsigned int*)src,
      (__attribute__((address_space(3))) unsigned int*)dst, 16, 0, 0);
}

// ---------------- fused weight prep: fp32->bf16 (+ transposes for 1x3 / 2x1 convs) -------
__device__ __forceinline__ void cvt4(const float* __restrict__ src,
                                     unsigned short* __restrict__ dst, int i) {
  float4 v = reinterpret_cast<const float4*>(src)[i];
  short4v o;
  o[0] = (short)f2bf(v.x); o[1] = (short)f2bf(v.y);
  o[2] = (short)f2bf(v.z); o[3] = (short)f2bf(v.w);
  reinterpret_cast<short4v*>(dst)[i] = o;
}

__global__ __launch_bounds__(256) void k_prep(
    const float* __restrict__ enc_w1, const float* __restrict__ enc_w2,
    const float* __restrict__ pc_w1, const float* __restrict__ pc_w4,
    const float* __restrict__ z2t_w, const float* __restrict__ c2p_w,
    const float* __restrict__ pc_w2, const float* __restrict__ pc_w3,
    unsigned short* __restrict__ w1b, unsigned short* __restrict__ w2b,
    unsigned short* __restrict__ pcw1b, unsigned short* __restrict__ pcw4b,
    unsigned short* __restrict__ z2tb, unsigned short* __restrict__ c2pb,
    unsigned short* __restrict__ w2t, unsigned short* __restrict__ w3t)
{
  const int b = blockIdx.x, tid = threadIdx.x;
  if (b < 48)        cvt4(enc_w1, w1b,   b * 256 + tid);
  else if (b < 560)  cvt4(enc_w2, w2b,   (b - 48) * 256 + tid);
  else if (b < 3120) cvt4(pc_w1,  pcw1b, (b - 560) * 256 + tid);
  else if (b < 5680) cvt4(pc_w4,  pcw4b, (b - 3120) * 256 + tid);
  else if (b < 5808) cvt4(z2t_w,  z2tb,  (b - 5680) * 256 + tid);
  else if (b < 6192) cvt4(c2p_w,  c2pb,  (b - 5808) * 256 + tid);
  else if (b < 10032) {
    // pc_w2 [5][co][ci][1][3] -> w2t [5][co][d*256+ci]
    const int e = (b - 6192) * 256 + tid;
    const int k5 = e / 196608, r = e % 196608;
    const int co = r / 768, kk = r % 768, d = kk >> 8, ci = kk & 255;
    w2t[e] = f2bf(pc_w2[((size_t)(k5 * 256 + co) * 256 + ci) * 3 + d]);
  } else {
    // pc_w3 [5][co][ci][2][1] -> w3t [5][co][s*256+ci]
    const int e = (b - 10032) * 256 + tid;
    const int k5 = e / 131072, r = e % 131072;
    const int co = r >> 9, kk = r & 511, s = kk >> 8, ci = kk & 255;
    w3t[e] = f2bf(pc_w3[((size_t)(k5 * 256 + co) * 256 + ci) * 2 + s]);
  }
}

// ---------------- conv2 + relu + mean-pool GEMM (single-buffer, proven 282us) ------------
// FROZEN. dbuf@64KB (r6), 512-thread/48KB (r8), A-direct (r10) all regressed.
__global__ __launch_bounds__(256) void k_enc2(
    const unsigned short* __restrict__ H1, const unsigned short* __restrict__ w2b,
    const float* __restrict__ b2, unsigned short* __restrict__ xout, int gbase)
{
  __shared__ char lds[32768];
  char* At = lds;            // 128 co rows x 8 granules (linear)
  char* Bt = lds + 16384;    // 128 pos rows x 8 granules (linear)
  const int tid = threadIdx.x;
  const int nwg = gridDim.x;
  int bid = blockIdx.x;
  int l = bid;
  if ((nwg & 7) == 0) { const int cpx = nwg >> 3; l = (bid & 7) * cpx + (bid >> 3); }
  const int m0 = (l & 15) * 128;
  const int by = l >> 4;
  const int w = tid >> 6, lane = tid & 63, lr = lane & 15, lg = lane >> 4;
  const int wm = w & 1, wn = w >> 1;
  const int srow = lane >> 3, sslot = lane & 7;
  f32x4 acc[4][4];
  for (int i = 0; i < 4; i++) for (int j = 0; j < 4; j++) acc[i][j] = (f32x4)0.f;
  for (int kb = 0; kb < 4; kb++) {
    __syncthreads();
#pragma unroll
    for (int c = 0; c < 4; c++) {
      const int rbase = w * 32 + c * 8;
      const int row = rbase + srow;
      gload16(w2b + (size_t)(m0 + row) * 256 + kb * 64 + ((sslot ^ (row & 7)) * 8),
              At + rbase * 128);
    }
#pragma unroll
    for (int c = 0; c < 4; c++) {
      const int rbase = w * 32 + c * 8;
      const int row = rbase + srow;
      gload16(H1 + (size_t)(by * 128 + row) * 256 + kb * 64 + ((sslot ^ (row & 7)) * 8),
              Bt + rbase * 128);
    }
    __syncthreads();
#pragma unroll
    for (int kk = 0; kk < 2; kk++) {
      const int gg = kk * 4 + lg;
      short8 bb[4];
#pragma unroll
      for (int nt = 0; nt < 4; nt++) {
        const int row = wn * 64 + nt * 16 + lr;
        bb[nt] = *reinterpret_cast<const short8*>(Bt + row * 128 + ((gg ^ (row & 7)) * 16));
      }
#pragma unroll
      for (int cot = 0; cot < 4; cot++) {
        const int row = wm * 64 + cot * 16 + lr;
        const short8 a = *reinterpret_cast<const short8*>(At + row * 128 + ((gg ^ (row & 7)) * 16));
#pragma unroll
        for (int nt = 0; nt < 4; nt++)
          acc[cot][nt] = mfma16(a, bb[nt], acc[cot][nt]);
      }
    }
  }
  // epilogue: relu(+b2), pool over this wave's 64 positions (= its patch)
  const int n = gbase + by * 2 + wn;
#pragma unroll
  for (int cot = 0; cot < 4; cot++) {
    const int cob = m0 + wm * 64 + cot * 16 + lg * 4;
    float4 bi = *reinterpret_cast<const float4*>(b2 + cob);
    const float bv[4] = { bi.x, bi.y, bi.z, bi.w };
    float s[4] = { 0.f, 0.f, 0.f, 0.f };
#pragma unroll
    for (int nt = 0; nt < 4; nt++)
#pragma unroll
      for (int r = 0; r < 4; r++)
        s[r] += fmaxf(acc[cot][nt][r] + bv[r], 0.f);
#pragma unroll
    for (int r = 0; r < 4; r++)
#pragma unroll
      for (int mk = 1; mk < 16; mk <<= 1)
        s[r] += __shfl_xor(s[r], mk, 64);
    if (lr == 0) {
      short4v o;
#pragma unroll
      for (int r = 0; r < 4; r++) o[r] = (short)f2bf(s[r] * (1.f / 64.f));
      *reinterpret_cast<short4v*>(xout + (size_t)n * 2048 + cob) = o;
    }
  }
}

// ---------------- latents mean over 49 patches ----------------
__global__ __launch_bounds__(256) void k_out2(const unsigned short* __restrict__ x,
                                              float* __restrict__ out) {
  const int ch = blockIdx.x * 256 + threadIdx.x;
  const int b = blockIdx.y;
  float s = 0.f;
  for (int p = 0; p < 49; p++) s += bf2f(x[(size_t)(b * 49 + p) * 2048 + ch]);
  out[1 + b * 2048 + ch] = s * (1.f / 49.f);
}

// ---------------- fused 1x3 + 2x1 conv block (one image per block) ----------------
// r9 logic (correctness-verified) with r10's diagnosed perf bug fixed: A operands are
// STAGED through LDS in BOTH phases (2-barrier gload16 loop), never read direct-global
// inside the MFMA chain. y2 lives entirely in LDS; in-place y3 -> y1 buffer.
__global__ __launch_bounds__(256) void k_conv23(
    const unsigned short* __restrict__ y1, const unsigned short* __restrict__ w2tk,
    const float* __restrict__ b2, const unsigned short* __restrict__ w3tk,
    const float* __restrict__ b3, unsigned short* __restrict__ y3)
{
  __shared__ char Ast[32768];   // staged A tile: 256 rows x 128B
  __shared__ char Bst[8192];    // phase-1 gather tile: 64 rows x 128B
  __shared__ char y2l[32768];   // y2: 64 rows x 512B, granule-XOR swizzled
  const int tid = threadIdx.x;
  const int b = blockIdx.x;
  const int nb = b * 49;
  const int w = tid >> 6, lane = tid & 63, lr = lane & 15, lg = lane >> 4;
  const int srow = lane >> 3, sslot = lane & 7;
  f32x4 acc[4][4];
  for (int i = 0; i < 4; i++) for (int j = 0; j < 4; j++) acc[i][j] = (f32x4)0.f;

  // ---- phase 1: conv 1x3, K=768, A staged ----
  for (int kb = 0; kb < 12; kb++) {
    __syncthreads();
#pragma unroll
    for (int c = 0; c < 8; c++) {
      const int rbase = w * 64 + c * 8;
      const int row = rbase + srow;
      gload16(w2tk + (size_t)row * 768 + kb * 64 + ((sslot ^ (row & 7)) * 8),
              Ast + rbase * 128);
    }
    for (int g = tid; g < 512; g += 256) {
      const int row = g >> 3, slot = g & 7;
      const int k = kb * 64 + slot * 8;
      const int d = k >> 8, ci = k & 255;
      short8 v = (short8)(short)0;
      if (row < 49) {
        const int wc = row % 7 + d - 1;
        if ((unsigned)wc <= 6u)
          v = *reinterpret_cast<const short8*>(y1 + (size_t)(nb + row + d - 1) * 256 + ci);
      }
      *reinterpret_cast<short8*>(Bst + row * 128 + ((slot ^ (row & 7)) * 16)) = v;
    }
    __syncthreads();
#pragma unroll
    for (int kk = 0; kk < 2; kk++) {
      const int gg = kk * 4 + lg;
      short8 bb[4];
#pragma unroll
      for (int nt = 0; nt < 4; nt++) {
        const int row = nt * 16 + lr;
        bb[nt] = *reinterpret_cast<const short8*>(Bst + row * 128 + ((gg ^ (row & 7)) * 16));
      }
#pragma unroll
      for (int cot = 0; cot < 4; cot++) {
        const int arow = w * 64 + cot * 16 + lr;
        const short8 a = *reinterpret_cast<const short8*>(Ast + arow * 128 + ((gg ^ (arow & 7)) * 16));
#pragma unroll
        for (int nt = 0; nt < 4; nt++)
          acc[cot][nt] = mfma16(a, bb[nt], acc[cot][nt]);
      }
    }
  }
  // epilogue 1: y2 = relu(+b2) -> y2l (granule-swizzled); pad rows benign (phase-1 B pad = 0)
#pragma unroll
  for (int cot = 0; cot < 4; cot++) {
    const int cob = w * 64 + cot * 16 + lg * 4;
    float4 bi = *reinterpret_cast<const float4*>(b2 + cob);
    const float bv[4] = { bi.x, bi.y, bi.z, bi.w };
    const int g2 = cob >> 3;
#pragma unroll
    for (int nt = 0; nt < 4; nt++) {
      const int row = nt * 16 + lr;
      short4v o;
#pragma unroll
      for (int r = 0; r < 4; r++)
        o[r] = (short)f2bf(fmaxf(acc[cot][nt][r] + bv[r], 0.f));
      const int sw = (g2 & ~7) | ((g2 & 7) ^ (row & 7));
      *reinterpret_cast<short4v*>(y2l + row * 512 + sw * 16 + (cob & 7) * 2) = o;
    }
  }
  __syncthreads();

  // ---- phase 2: conv 2x1, K=512, A staged, B from y2l ----
  f32x4 ac2[4][4];
  for (int i = 0; i < 4; i++) for (int j = 0; j < 4; j++) ac2[i][j] = (f32x4)0.f;
  for (int kb = 0; kb < 8; kb++) {
    __syncthreads();
#pragma unroll
    for (int c = 0; c < 8; c++) {
      const int rbase = w * 64 + c * 8;
      const int row = rbase + srow;
      gload16(w3tk + (size_t)row * 512 + kb * 64 + ((sslot ^ (row & 7)) * 8),
              Ast + rbase * 128);
    }
    __syncthreads();
    const int soff = (kb >= 4) ? 0 : -7;   // s=1 rows, s=0 rows-7
#pragma unroll
    for (int kk = 0; kk < 2; kk++) {
      const int gg = kk * 4 + lg;
      const int gci = (kb * 8 + gg) & 31;  // ci-granule within y2l row
      short8 bb[4];
#pragma unroll
      for (int nt = 0; nt < 4; nt++) {
        const int nout = nt * 16 + lr;
        const int ry = nout + soff;
        short8 v = (short8)(short)0;
        if (ry >= 0) {
          const int sw = (gci & ~7) | ((gci & 7) ^ (ry & 7));
          v = *reinterpret_cast<const short8*>(y2l + ry * 512 + sw * 16);
        }
        bb[nt] = v;
      }
#pragma unroll
      for (int cot = 0; cot < 4; cot++) {
        const int arow = w * 64 + cot * 16 + lr;
        const short8 a = *reinterpret_cast<const short8*>(Ast + arow * 128 + ((gg ^ (arow & 7)) * 16));
#pragma unroll
        for (int nt = 0; nt < 4; nt++)
          ac2[cot][nt] = mfma16(a, bb[nt], ac2[cot][nt]);
      }
    }
  }
  // epilogue 2: y3 = relu(+b3) -> global (rows < 49 only; in-place over y1 is block-local)
#pragma unroll
  for (int cot = 0; cot < 4; cot++) {
    const int cob = w * 64 + cot * 16 + lg * 4;
    float4 bi = *reinterpret_cast<const float4*>(b3 + cob);
    const float bv[4] = { bi.x, bi.y, bi.z, bi.w };
#pragma unroll
    for (int nt = 0; nt < 4; nt++) {
      const int nout = nt * 16 + lr;
      if (nout < 49) {
        short4v o;
#pragma unroll
        for (int r = 0; r < 4; r++)
          o[r] = (short)f2bf(fmaxf(ac2[cot][nt][r] + bv[r], 0.f));
        *reinterpret_cast<short4v*>(y3 + (size_t)(nb + nout) * 256 + cob) = o;
      }
    }
  }
}

// ---------------- generic bf16 MFMA GEMM ----------------
// MODE 0: B row n = in + n*bstride (gload-lds, dbuf 2-phase, BK 64/128/256)
// MODE 4: masked im2col from images (VALU staged, BK=64)
template<int M_BLK, int BK, int MODE, bool BIAS, bool RELU, bool RESID, bool SCALE, bool OBF16>
__global__ __launch_bounds__(256) void k_gemm(
    const unsigned short* __restrict__ in, const unsigned short* __restrict__ W,
    const float* __restrict__ bias, float* __restrict__ outf,
    unsigned short* __restrict__ outb, const unsigned short* __restrict__ res,
    int M, int K, int bstride, int aux, float scale,
    int wzs, int bzs, int ozs,
    const float* __restrict__ img, const int* __restrict__ rndp)
{
  constexpr int MF = M_BLK / 64;
  constexpr int GPR = BK / 8;          // 16B granules per row
  constexpr int ROWS = 64 / GPR;       // rows per wave gload16
  constexpr int RS = BK * 2;           // row stride bytes
  constexpr int CHA = (M_BLK / 4) / ROWS;
  constexpr int CHB = 16 / ROWS;
  constexpr int AG = M_BLK * 8;        // A granules per K-block (BK=64 VALU path)
  constexpr bool DBUF = (MODE == 0);
  constexpr int BUF = (M_BLK + 64) * RS;
  __shared__ char ldsb[(DBUF ? 2 : 1) * BUF];
  const int tid = threadIdx.x;
  const int z = blockIdx.z;
  W += (size_t)z * wzs;
  if (BIAS) bias += (size_t)z * bzs;
  const int m0 = blockIdx.x * M_BLK;
  const int n0 = blockIdx.y * 64;
  const int w = tid >> 6, lane = tid & 63, lr = lane & 15, lg = lane >> 4;
  const int srow = lane / GPR, sslot = lane % GPR;
  int pb = 0, pR = 0, pC = 0, roff = 0, coff = 0;
  if constexpr (MODE == 4) {
    const int pn = aux + blockIdx.y;
    pb = pn / 49; const int prc = pn % 49; pR = prc / 7; pC = prc % 7;
    const int rv = rndp[pn];
    roff = rv >> 2; coff = rv & 3;
  }
  f32x4 acc[MF][4];
  for (int mf = 0; mf < MF; mf++) for (int nt = 0; nt < 4; nt++) acc[mf][nt] = (f32x4)0.f;
  const int KB = K / BK;

  auto stageA = [&](char* At, int kb) {
#pragma unroll
    for (int c = 0; c < CHA; c++) {
      const int rbase = w * (M_BLK / 4) + c * ROWS;
      const int row = rbase + srow;
      gload16(W + (size_t)(m0 + row) * K + kb * BK + ((sslot ^ (row & 7)) * 8),
              At + rbase * RS);
    }
  };
  auto compute = [&](const char* At, const char* Bt) {
#pragma unroll
    for (int kk = 0; kk < BK / 32; kk++) {
      short8 a[MF], bb[4];
      const int gg = kk * 4 + lg;
#pragma unroll
      for (int mf = 0; mf < MF; mf++) {
        const int row = w * (M_BLK / 4) + mf * 16 + lr;
        a[mf] = *reinterpret_cast<const short8*>(At + row * RS + ((gg ^ (row & 7)) * 16));
      }
#pragma unroll
      for (int nt = 0; nt < 4; nt++) {
        const int row = nt * 16 + lr;
        bb[nt] = *reinterpret_cast<const short8*>(Bt + row * RS + ((gg ^ (row & 7)) * 16));
      }
#pragma unroll
      for (int mf = 0; mf < MF; mf++)
#pragma unroll
        for (int nt = 0; nt < 4; nt++)
          acc[mf][nt] = mfma16(a[mf], bb[nt], acc[mf][nt]);
    }
  };

  if constexpr (DBUF) {
    auto stageB = [&](char* Bt, int kb) {
#pragma unroll
      for (int c = 0; c < CHB; c++) {
        const int rbase = w * 16 + c * ROWS;
        const int row = rbase + srow;
        const int n = n0 + row;
        gload16(in + (size_t)n * bstride + kb * BK + ((sslot ^ (row & 7)) * 8),
                Bt + rbase * RS);
      }
    };
    stageA(ldsb, 0);
    stageB(ldsb + M_BLK * RS, 0);
    __syncthreads();
    int cur = 0;
    for (int kb = 0; kb < KB; kb++) {
      if (kb + 1 < KB) {
        char* nb = ldsb + (cur ^ 1) * BUF;
        stageA(nb, kb + 1);
        stageB(nb + M_BLK * RS, kb + 1);
      }
      char* cb = ldsb + cur * BUF;
      compute(cb, cb + M_BLK * RS);
      __syncthreads();
      cur ^= 1;
    }
  } else {
    // BK == 64 (MODE 4)
    for (int kb = 0; kb < KB; kb++) {
      __syncthreads();
      stageA(ldsb, kb);
      char* Bt = ldsb + M_BLK * RS;
      for (int g = AG + tid; g < AG + 512; g += 256) {
        const int h = g - AG, row = h >> 3, slot = h & 7;
        short8 v = (short8)(short)0;
        {
          // masked im2col: row = p in patch, gr = kb*8+slot, k = ci*64+ky*8+kx
          const int p = row;
          const int gr = kb * 8 + slot;
          const int ci = gr >> 3, ky = gr & 7;
          const int oy = p >> 3, ox = p & 7;
          const int y = oy * 8 + ky;
          const float* src = img + (((size_t)(pb * 3 + ci) * 256 + (size_t)(pR * 32 + y)) * 256
                                    + pC * 32 + ox * 8);
          float4 v0 = *reinterpret_cast<const float4*>(src);
          float4 v1 = *reinterpret_cast<const float4*>(src + 4);
          const bool rok = (y >= roff) && (y < roff + 60);
          float vals[8] = { v0.x, v0.y, v0.z, v0.w, v1.x, v1.y, v1.z, v1.w };
          const int x0 = ox * 8;
#pragma unroll
          for (int q = 0; q < 8; q++) {
            const int xx = x0 + q;
            const bool ok = rok && (xx >= coff) && (xx < coff + 60);
            v[q] = (short)f2bf(ok ? vals[q] : -1.0f);
          }
        }
        *reinterpret_cast<short8*>(Bt + row * RS + ((slot ^ (row & 7)) * 16)) = v;
      }
      __syncthreads();
      compute(ldsb, ldsb + M_BLK * RS);
    }
  }

#pragma unroll
  for (int mf = 0; mf < MF; mf++) {
    const int mb = m0 + w * (M_BLK / 4) + mf * 16 + lg * 4;
    float bv[4] = {0.f, 0.f, 0.f, 0.f};
    if constexpr (BIAS) {
      float4 t4 = *reinterpret_cast<const float4*>(bias + mb);
      bv[0] = t4.x; bv[1] = t4.y; bv[2] = t4.z; bv[3] = t4.w;
    }
#pragma unroll
    for (int nt = 0; nt < 4; nt++) {
      const size_t nn = (size_t)(n0 + nt * 16 + lr);
      const size_t off = nn * (size_t)M + mb + (size_t)z * ozs;
      float v[4];
#pragma unroll
      for (int r = 0; r < 4; r++) {
        v[r] = acc[mf][nt][r] + bv[r];
        if (SCALE) v[r] *= scale;
      }
      if (RESID) {
        short4v rv = *reinterpret_cast<const short4v*>(res + off);
#pragma unroll
        for (int r = 0; r < 4; r++) v[r] += bf2f((unsigned short)rv[r]);
      }
#pragma unroll
      for (int r = 0; r < 4; r++) if (RELU) v[r] = fmaxf(v[r], 0.f);
      if (OBF16) {
        short4v o;
#pragma unroll
        for (int r = 0; r < 4; r++) o[r] = (short)f2bf(v[r]);
        *reinterpret_cast<short4v*>(outb + off) = o;
      } else {
        float4 o; o.x = v[0]; o.y = v[1]; o.z = v[2]; o.w = v[3];
        *reinterpret_cast<float4*>(outf + off) = o;
      }
    }
  }
}

// ---------------- fused streaming logits + partial log-sum-exp ----------------
// Grid (63, 7). Block (bi, tz): 64 pred rows, targ tiles [tz*7, tz*7+7).
__global__ __launch_bounds__(256) void k_lse2(
    const unsigned short* __restrict__ predsb, const unsigned short* __restrict__ targ,
    float* __restrict__ pm, float* __restrict__ ps, float* __restrict__ zlab)
{
  __shared__ char At[8192];   // targ tile: 64 rows x 128B
  __shared__ char Bt[8192];   // preds tile: 64 rows x 128B
  __shared__ float redM[4][64], redS[4][64];
  const int tid = threadIdx.x;
  const int R0 = blockIdx.x * 64;
  const int tz = blockIdx.y;
  const int t0 = tz * 7;
  const int t1 = t0 + 7;
  int ip, base, cd7;
  if (R0 < 1792)      { ip = 0; base = 0;    cd7 = 28; }
  else if (R0 < 3136) { ip = 1; base = 1792; cd7 = 21; }
  else                { ip = 2; base = 3136; cd7 = 14; }
  const int lab7 = 7 * (ip + 3);
  const unsigned short* preds = predsb + (size_t)ip * 200704;
  const int w = tid >> 6, lane = tid & 63, lr = lane & 15, lg = lane >> 4;
  const int srow = lane >> 3, sslot = lane & 7;

#pragma unroll
  for (int c = 0; c < 2; c++) {
    const int rbase = w * 16 + c * 8;
    const int row = rbase + srow;
    const int rr = R0 - base + row;
    const int np = (rr / cd7) * 49 + (rr % cd7);
    gload16(preds + (size_t)np * 64 + ((sslot ^ (row & 7)) * 8), Bt + rbase * 128);
  }

  int labv[4];
#pragma unroll
  for (int nt = 0; nt < 4; nt++) {
    const int nc = R0 - base + nt * 16 + lr;
    labv[nt] = (nc / cd7) * 49 + (nc % cd7) + lab7;
  }
  float mrun[4] = {-1e30f, -1e30f, -1e30f, -1e30f};
  float srun[4] = {0.f, 0.f, 0.f, 0.f};

  for (int t = t0; t < t1; t++) {
#pragma unroll
    for (int c = 0; c < 2; c++) {
      const int rbase = w * 16 + c * 8;
      const int row = rbase + srow;
      gload16(targ + (size_t)(t * 64 + row) * 64 + ((sslot ^ (row & 7)) * 8),
              At + rbase * 128);
    }
    __syncthreads();
    f32x4 av[4];
#pragma unroll
    for (int nt = 0; nt < 4; nt++) av[nt] = (f32x4)0.f;
#pragma unroll
    for (int kk = 0; kk < 2; kk++) {
      const int gg = kk * 4 + lg;
      const int arow = w * 16 + lr;
      const short8 a = *reinterpret_cast<const short8*>(At + arow * 128 + ((gg ^ (arow & 7)) * 16));
#pragma unroll
      for (int nt = 0; nt < 4; nt++) {
        const int brow = nt * 16 + lr;
        const short8 b = *reinterpret_cast<const short8*>(Bt + brow * 128 + ((gg ^ (brow & 7)) * 16));
        av[nt] = mfma16(a, b, av[nt]);
      }
    }
    const int mg = t * 64 + w * 16 + lg * 4;
#pragma unroll
    for (int nt = 0; nt < 4; nt++) {
      float v0 = av[nt][0], v1 = av[nt][1], v2 = av[nt][2], v3 = av[nt][3];
      if (mg + 0 == labv[nt]) zlab[R0 + nt * 16 + lr] = v0;
      if (mg + 1 == labv[nt]) zlab[R0 + nt * 16 + lr] = v1;
      if (mg + 2 == labv[nt]) zlab[R0 + nt * 16 + lr] = v2;
      if (mg + 3 == labv[nt]) zlab[R0 + nt * 16 + lr] = v3;
      const float vm = fmaxf(fmaxf(v0, v1), fmaxf(v2, v3));
      const float nm = fmaxf(mrun[nt], vm);
      srun[nt] = srun[nt] * __expf(mrun[nt] - nm)
               + __expf(v0 - nm) + __expf(v1 - nm) + __expf(v2 - nm) + __expf(v3 - nm);
      mrun[nt] = nm;
    }
    __syncthreads();
  }
#pragma unroll
  for (int nt = 0; nt < 4; nt++) {
#pragma unroll
    for (int mk = 16; mk < 64; mk <<= 1) {
      const float om = __shfl_xor(mrun[nt], mk, 64);
      const float os = __shfl_xor(srun[nt], mk, 64);
      const float nm = fmaxf(mrun[nt], om);
      srun[nt] = srun[nt] * __expf(mrun[nt] - nm) + os * __expf(om - nm);
      mrun[nt] = nm;
    }
    if (lg == 0) { redM[w][nt * 16 + lr] = mrun[nt]; redS[w][nt * 16 + lr] = srun[nt]; }
  }
  __syncthreads();
  if (tid < 64) {
    float m = redM[0][tid], s = redS[0][tid];
#pragma unroll
    for (int wv = 1; wv < 4; wv++) {
      const float om = redM[wv][tid], os = redS[wv][tid];
      const float nm = fmaxf(m, om);
      s = s * __expf(m - nm) + os * __expf(om - nm);
      m = nm;
    }
    pm[(R0 + tid) * 7 + tz] = m;
    ps[(R0 + tid) * 7 + tz] = s;
  }
}

__global__ __launch_bounds__(256) void k_loss_final(
    const float* __restrict__ pm, const float* __restrict__ ps,
    const float* __restrict__ zlab, float* __restrict__ out)
{
  __shared__ float red[256];
  const int tid = threadIdx.x;
  float acc = 0.f;
  for (int i = tid; i < 4032; i += 256) {
    float m = pm[i * 7], s = ps[i * 7];
#pragma unroll
    for (int j = 1; j < 7; j++) {
      const float om = pm[i * 7 + j], os = ps[i * 7 + j];
      const float nm = fmaxf(m, om);
      s = s * __expf(m - nm) + os * __expf(om - nm);
      m = nm;
    }
    const float loss = (m + __logf(s)) - zlab[i];
    const float wgt = (i < 1792) ? (1.f / 1792.f) : ((i < 3136) ? (1.f / 1344.f) : (1.f / 896.f));
    acc += loss * wgt;
  }
  red[tid] = acc;
  for (int off = 128; off > 0; off >>= 1) {
    __syncthreads();
    if (tid < off) red[tid] += red[tid + off];
  }
  if (tid == 0) out[0] = red[0];
}

extern "C" void kernel_launch(void* const* d_in, const int* in_sizes, int n_in,
                              void* d_out, int out_size, void* d_ws, size_t ws_size,
                              hipStream_t stream)
{
  (void)in_sizes; (void)n_in; (void)out_size;
  const float* images = (const float*)d_in[0];
  const int*   rnd    = (const int*)d_in[1];
  const float* enc_w1 = (const float*)d_in[2];
  const float* enc_b1 = (const float*)d_in[3];
  const float* enc_w2 = (const float*)d_in[4];
  const float* enc_b2 = (const float*)d_in[5];
  const float* pc_w1  = (const float*)d_in[6];
  const float* pc_b1  = (const float*)d_in[7];
  const float* pc_w2  = (const float*)d_in[8];
  const float* pc_b2  = (const float*)d_in[9];
  const float* pc_w3  = (const float*)d_in[10];
  const float* pc_b3  = (const float*)d_in[11];
  const float* pc_w4  = (const float*)d_in[12];
  const float* pc_b4  = (const float*)d_in[13];
  const float* z2t_w  = (const float*)d_in[14];
  const float* z2t_b  = (const float*)d_in[15];
  const float* c2p_w  = (const float*)d_in[16];
  const float* c2p_b  = (const float*)d_in[17];
  float* out = (float*)d_out;
  char* ws = (char*)d_ws;

  // ws layout (bytes)
  unsigned short* w1b    = (unsigned short*)(ws + 0);          //    98,304
  unsigned short* w2b    = (unsigned short*)(ws + 98304);      // 1,048,576
  unsigned short* z2tb   = (unsigned short*)(ws + 1146880);    //   262,144
  unsigned short* c2pb   = (unsigned short*)(ws + 1409024);    //   786,432
  unsigned short* w2t    = (unsigned short*)(ws + 2195456);    // 1,966,080
  unsigned short* w3t    = (unsigned short*)(ws + 4161536);    // 1,310,720
  unsigned short* targ   = (unsigned short*)(ws + 5472256);    //   401,408
  unsigned short* predsb = (unsigned short*)(ws + 5873664);    // 1,204,224
  unsigned short* y1b    = (unsigned short*)(ws + 7094016);    // 1,605,632
  unsigned short* pcw1b  = (unsigned short*)(ws + 10305280);   // 5,242,880
  unsigned short* pcw4b  = (unsigned short*)(ws + 15548160);   // 5,242,880
  unsigned short* xbuf   = (unsigned short*)(ws + 20791040);   // 12,845,056 (end 33,636,096)
  // loss partials overlay the y1b region (dead after PixelCNN)
  float*          pm     = (float*)(ws + 7094016);             //   112,896
  float*          psum   = (float*)(ws + 7206912);             //   112,896
  float*          zlab   = (float*)(ws + 7319808);             //    16,128

  k_prep<<<12592, 256, 0, stream>>>(enc_w1, enc_w2, pc_w1, pc_w4, z2t_w, c2p_w,
                                    pc_w2, pc_w3,
                                    w1b, w2b, pcw1b, pcw4b, z2tb, c2pb, w2t, w3t);

  // ---- encoder: GEMM1 (masked im2col fused) -> H1, then pooled conv2 GEMM ----
  const size_t h1_off = 33636352;                    // 16B-aligned, after xbuf
  const size_t per_patch = 64 * 256 * 2;             // 32 KB of H1 per patch
  unsigned short* H1;
  int CH;
  if (ws_size > h1_off + 2 * per_patch) {
    size_t avail = (ws_size - h1_off) / per_patch;
    CH = (int)(avail > 3136 ? 3136 : avail) & ~1;
    H1 = (unsigned short*)(ws + h1_off);
  } else {
    // fallback: reuse dead y1b region + beyond (3.2 MB -> 98 patches)
    H1 = y1b;
    CH = 98;
  }
  for (int base = 0; base < 3136; base += CH) {
    const int c = (3136 - base) < CH ? (3136 - base) : CH;
    k_gemm<256, 64, 4, true, true, false, false, true><<<dim3(1, c), 256, 0, stream>>>(
        nullptr, w1b, enc_b1, nullptr, H1, nullptr, 256, 192, 0, base, 1.f,
        0, 0, 0, images, rnd);
    k_enc2<<<16 * (c / 2), 256, 0, stream>>>(H1, w2b, enc_b2, xbuf, base);
  }

  k_out2<<<dim3(8, 64), 256, 0, stream>>>(xbuf, out);
  k_gemm<64, 256, 0, true, false, false, false, true><<<dim3(1, 49), 256, 0, stream>>>(
      xbuf, z2tb, z2t_b, nullptr, targ, nullptr, 64, 2048, 2048, 0, 1.f, 0, 0, 0,
      nullptr, nullptr);

  // PixelCNN: 5 residual blocks (conv1 GEMM, fused conv2+conv3, conv4 GEMM)
  for (int k = 0; k < 5; k++) {
    k_gemm<64, 256, 0, true, true, false, false, true><<<dim3(4, 49), 256, 0, stream>>>(
        xbuf, pcw1b + (size_t)k * 524288, pc_b1 + k * 256, nullptr, y1b, nullptr,
        256, 2048, 2048, 0, 1.f, 0, 0, 0, nullptr, nullptr);
    k_conv23<<<64, 256, 0, stream>>>(
        y1b, w2t + (size_t)k * 196608, pc_b2 + k * 256,
        w3t + (size_t)k * 131072, pc_b3 + k * 256, y1b);
    k_gemm<128, 64, 0, true, true, true, false, true><<<dim3(16, 49), 256, 0, stream>>>(
        y1b, pcw4b + (size_t)k * 524288, pc_b4 + k * 2048, nullptr, xbuf, xbuf,
        2048, 256, 256, 0, 1.f, 0, 0, 0, nullptr, nullptr);
  }

  // all 3 preds in one z-batched launch (xbuf still live)
  k_gemm<64, 256, 0, true, false, false, true, true><<<dim3(1, 49, 3), 256, 0, stream>>>(
      xbuf, c2pb, c2p_b, nullptr, predsb, nullptr, 64, 2048, 2048, 0, 0.1f,
      131072, 64, 200704, nullptr, nullptr);

  // fused streaming logits+LSE, t-split 7-way (y1b region is dead by now)
  k_lse2<<<dim3(63, 7), 256, 0, stream>>>(predsb, targ, pm, psum, zlab);
  k_loss_final<<<1, 256, 0, stream>>>(pm, psum, zlab, out);
}

// Round 13
// 636.217 us; speedup vs baseline: 1.0317x; 1.0317x over previous
//
#include <hip/hip_runtime.h>
#include <hip/hip_bf16.h>
#include <cstdint>
#include <cstddef>

typedef __attribute__((ext_vector_type(8))) short short8;
typedef __attribute__((ext_vector_type(4))) short short4v;
typedef __attribute__((ext_vector_type(4))) float f32x4;

__device__ __forceinline__ float bf2f(unsigned short u) {
  union { unsigned int i; float f; } v; v.i = ((unsigned int)u) << 16; return v.f;
}
__device__ __forceinline__ unsigned short f2bf(float f) {
  union { float f; unsigned int i; } v; v.f = f;
  unsigned int x = v.i;
  return (unsigned short)((x + 0x7fffu + ((x >> 16) & 1u)) >> 16);
}
__device__ __forceinline__ f32x4 mfma16(short8 a, short8 b, f32x4 c) {
  return __builtin_amdgcn_mfma_f32_16x16x32_bf16(a, b, c, 0, 0, 0);
}
// async global->LDS, 16B/lane. dst must be wave-uniform; HW writes dst + lane*16.
__device__ __forceinline__ void gload16(const void* src, void* dst) {
  __builtin_amdgcn_global_load_lds(
      (const __attribute__((address_space(1))) unsigned int*)src,
      (__attribute__((address_space(3))) unsigned int*)dst, 16, 0, 0);
}

// ---------------- fused weight prep: fp32->bf16 (+ transposes for 1x3 / 2x1 convs) -------
__device__ __forceinline__ void cvt4(const float* __restrict__ src,
                                     unsigned short* __restrict__ dst, int i) {
  float4 v = reinterpret_cast<const float4*>(src)[i];
  short4v o;
  o[0] = (short)f2bf(v.x); o[1] = (short)f2bf(v.y);
  o[2] = (short)f2bf(v.z); o[3] = (short)f2bf(v.w);
  reinterpret_cast<short4v*>(dst)[i] = o;
}

__global__ __launch_bounds__(256) void k_prep(
    const float* __restrict__ enc_w1, const float* __restrict__ enc_w2,
    const float* __restrict__ pc_w1, const float* __restrict__ pc_w4,
    const float* __restrict__ z2t_w, const float* __restrict__ c2p_w,
    const float* __restrict__ pc_w2, const float* __restrict__ pc_w3,
    unsigned short* __restrict__ w1b, unsigned short* __restrict__ w2b,
    unsigned short* __restrict__ pcw1b, unsigned short* __restrict__ pcw4b,
    unsigned short* __restrict__ z2tb, unsigned short* __restrict__ c2pb,
    unsigned short* __restrict__ w2t, unsigned short* __restrict__ w3t)
{
  const int b = blockIdx.x, tid = threadIdx.x;
  if (b < 48)        cvt4(enc_w1, w1b,   b * 256 + tid);
  else if (b < 560)  cvt4(enc_w2, w2b,   (b - 48) * 256 + tid);
  else if (b < 3120) cvt4(pc_w1,  pcw1b, (b - 560) * 256 + tid);
  else if (b < 5680) cvt4(pc_w4,  pcw4b, (b - 3120) * 256 + tid);
  else if (b < 5808) cvt4(z2t_w,  z2tb,  (b - 5680) * 256 + tid);
  else if (b < 6192) cvt4(c2p_w,  c2pb,  (b - 5808) * 256 + tid);
  else if (b < 10032) {
    // pc_w2 [5][co][ci][1][3] -> w2t [5][co][d*256+ci]
    const int e = (b - 6192) * 256 + tid;
    const int k5 = e / 196608, r = e % 196608;
    const int co = r / 768, kk = r % 768, d = kk >> 8, ci = kk & 255;
    w2t[e] = f2bf(pc_w2[((size_t)(k5 * 256 + co) * 256 + ci) * 3 + d]);
  } else {
    // pc_w3 [5][co][ci][2][1] -> w3t [5][co][s*256+ci]
    const int e = (b - 10032) * 256 + tid;
    const int k5 = e / 131072, r = e % 131072;
    const int co = r >> 9, kk = r & 511, s = kk >> 8, ci = kk & 255;
    w3t[e] = f2bf(pc_w3[((size_t)(k5 * 256 + co) * 256 + ci) * 2 + s]);
  }
}

// ---------------- conv2 + relu + mean-pool GEMM (single-buffer, proven 282us) ------------
// FROZEN. dbuf@64KB (r6), 512-thread/48KB (r8), A-direct (r10) all regressed.
__global__ __launch_bounds__(256) void k_enc2(
    const unsigned short* __restrict__ H1, const unsigned short* __restrict__ w2b,
    const float* __restrict__ b2, unsigned short* __restrict__ xout, int gbase)
{
  __shared__ char lds[32768];
  char* At = lds;            // 128 co rows x 8 granules (linear)
  char* Bt = lds + 16384;    // 128 pos rows x 8 granules (linear)
  const int tid = threadIdx.x;
  const int nwg = gridDim.x;
  int bid = blockIdx.x;
  int l = bid;
  if ((nwg & 7) == 0) { const int cpx = nwg >> 3; l = (bid & 7) * cpx + (bid >> 3); }
  const int m0 = (l & 15) * 128;
  const int by = l >> 4;
  const int w = tid >> 6, lane = tid & 63, lr = lane & 15, lg = lane >> 4;
  const int wm = w & 1, wn = w >> 1;
  const int srow = lane >> 3, sslot = lane & 7;
  f32x4 acc[4][4];
  for (int i = 0; i < 4; i++) for (int j = 0; j < 4; j++) acc[i][j] = (f32x4)0.f;
  for (int kb = 0; kb < 4; kb++) {
    __syncthreads();
#pragma unroll
    for (int c = 0; c < 4; c++) {
      const int rbase = w * 32 + c * 8;
      const int row = rbase + srow;
      gload16(w2b + (size_t)(m0 + row) * 256 + kb * 64 + ((sslot ^ (row & 7)) * 8),
              At + rbase * 128);
    }
#pragma unroll
    for (int c = 0; c < 4; c++) {
      const int rbase = w * 32 + c * 8;
      const int row = rbase + srow;
      gload16(H1 + (size_t)(by * 128 + row) * 256 + kb * 64 + ((sslot ^ (row & 7)) * 8),
              Bt + rbase * 128);
    }
    __syncthreads();
#pragma unroll
    for (int kk = 0; kk < 2; kk++) {
      const int gg = kk * 4 + lg;
      short8 bb[4];
#pragma unroll
      for (int nt = 0; nt < 4; nt++) {
        const int row = wn * 64 + nt * 16 + lr;
        bb[nt] = *reinterpret_cast<const short8*>(Bt + row * 128 + ((gg ^ (row & 7)) * 16));
      }
#pragma unroll
      for (int cot = 0; cot < 4; cot++) {
        const int row = wm * 64 + cot * 16 + lr;
        const short8 a = *reinterpret_cast<const short8*>(At + row * 128 + ((gg ^ (row & 7)) * 16));
#pragma unroll
        for (int nt = 0; nt < 4; nt++)
          acc[cot][nt] = mfma16(a, bb[nt], acc[cot][nt]);
      }
    }
  }
  // epilogue: relu(+b2), pool over this wave's 64 positions (= its patch)
  const int n = gbase + by * 2 + wn;
#pragma unroll
  for (int cot = 0; cot < 4; cot++) {
    const int cob = m0 + wm * 64 + cot * 16 + lg * 4;
    float4 bi = *reinterpret_cast<const float4*>(b2 + cob);
    const float bv[4] = { bi.x, bi.y, bi.z, bi.w };
    float s[4] = { 0.f, 0.f, 0.f, 0.f };
#pragma unroll
    for (int nt = 0; nt < 4; nt++)
#pragma unroll
      for (int r = 0; r < 4; r++)
        s[r] += fmaxf(acc[cot][nt][r] + bv[r], 0.f);
#pragma unroll
    for (int r = 0; r < 4; r++)
#pragma unroll
      for (int mk = 1; mk < 16; mk <<= 1)
        s[r] += __shfl_xor(s[r], mk, 64);
    if (lr == 0) {
      short4v o;
#pragma unroll
      for (int r = 0; r < 4; r++) o[r] = (short)f2bf(s[r] * (1.f / 64.f));
      *reinterpret_cast<short4v*>(xout + (size_t)n * 2048 + cob) = o;
    }
  }
}

// ---------------- latents mean over 49 patches ----------------
__global__ __launch_bounds__(256) void k_out2(const unsigned short* __restrict__ x,
                                              float* __restrict__ out) {
  const int ch = blockIdx.x * 256 + threadIdx.x;
  const int b = blockIdx.y;
  float s = 0.f;
  for (int p = 0; p < 49; p++) s += bf2f(x[(size_t)(b * 49 + p) * 2048 + ch]);
  out[1 + b * 2048 + ch] = s * (1.f / 49.f);
}

// ---------------- generic bf16 MFMA GEMM with gather modes ----------------
// MODE 0: B row n = in + n*bstride (gload-lds, dbuf 2-phase, BK 64 or 128)
// MODE 1: 1x3 width conv gather; MODE 2: 2x1 height conv gather (VALU staged, BK=64)
// MODE 4: masked im2col from images (VALU staged, BK=64)
template<int M_BLK, int BK, int MODE, bool BIAS, bool RELU, bool RESID, bool SCALE, bool OBF16>
__global__ __launch_bounds__(256) void k_gemm(
    const unsigned short* __restrict__ in, const unsigned short* __restrict__ W,
    const float* __restrict__ bias, float* __restrict__ outf,
    unsigned short* __restrict__ outb, const unsigned short* __restrict__ res,
    int M, int K, int bstride, int aux, float scale,
    int wzs, int bzs, int ozs,
    const float* __restrict__ img, const int* __restrict__ rndp)
{
  constexpr int MF = M_BLK / 64;
  constexpr int GPR = BK / 8;          // 16B granules per row
  constexpr int ROWS = 64 / GPR;       // rows per wave gload16
  constexpr int RS = BK * 2;           // row stride bytes
  constexpr int CHA = (M_BLK / 4) / ROWS;
  constexpr int CHB = 16 / ROWS;
  constexpr int AG = M_BLK * 8;        // A granules per K-block (BK=64 VALU path)
  constexpr bool DBUF = (MODE == 0);
  constexpr int BUF = (M_BLK + 64) * RS;
  __shared__ char ldsb[(DBUF ? 2 : 1) * BUF];
  const int tid = threadIdx.x;
  const int z = blockIdx.z;
  W += (size_t)z * wzs;
  if (BIAS) bias += (size_t)z * bzs;
  const int m0 = blockIdx.x * M_BLK;
  const int n0 = blockIdx.y * 64;
  const int w = tid >> 6, lane = tid & 63, lr = lane & 15, lg = lane >> 4;
  const int srow = lane / GPR, sslot = lane % GPR;
  int pb = 0, pR = 0, pC = 0, roff = 0, coff = 0;
  if constexpr (MODE == 4) {
    const int pn = aux + blockIdx.y;
    pb = pn / 49; const int prc = pn % 49; pR = prc / 7; pC = prc % 7;
    const int rv = rndp[pn];
    roff = rv >> 2; coff = rv & 3;
  }
  f32x4 acc[MF][4];
  for (int mf = 0; mf < MF; mf++) for (int nt = 0; nt < 4; nt++) acc[mf][nt] = (f32x4)0.f;
  const int KB = K / BK;

  auto stageA = [&](char* At, int kb) {
#pragma unroll
    for (int c = 0; c < CHA; c++) {
      const int rbase = w * (M_BLK / 4) + c * ROWS;
      const int row = rbase + srow;
      gload16(W + (size_t)(m0 + row) * K + kb * BK + ((sslot ^ (row & 7)) * 8),
              At + rbase * RS);
    }
  };
  auto compute = [&](const char* At, const char* Bt) {
#pragma unroll
    for (int kk = 0; kk < BK / 32; kk++) {
      short8 a[MF], bb[4];
      const int gg = kk * 4 + lg;
#pragma unroll
      for (int mf = 0; mf < MF; mf++) {
        const int row = w * (M_BLK / 4) + mf * 16 + lr;
        a[mf] = *reinterpret_cast<const short8*>(At + row * RS + ((gg ^ (row & 7)) * 16));
      }
#pragma unroll
      for (int nt = 0; nt < 4; nt++) {
        const int row = nt * 16 + lr;
        bb[nt] = *reinterpret_cast<const short8*>(Bt + row * RS + ((gg ^ (row & 7)) * 16));
      }
#pragma unroll
      for (int mf = 0; mf < MF; mf++)
#pragma unroll
        for (int nt = 0; nt < 4; nt++)
          acc[mf][nt] = mfma16(a[mf], bb[nt], acc[mf][nt]);
    }
  };

  if constexpr (DBUF) {
    auto stageB = [&](char* Bt, int kb) {
#pragma unroll
      for (int c = 0; c < CHB; c++) {
        const int rbase = w * 16 + c * ROWS;
        const int row = rbase + srow;
        const int n = n0 + row;
        gload16(in + (size_t)n * bstride + kb * BK + ((sslot ^ (row & 7)) * 8),
                Bt + rbase * RS);
      }
    };
    stageA(ldsb, 0);
    stageB(ldsb + M_BLK * RS, 0);
    __syncthreads();
    int cur = 0;
    for (int kb = 0; kb < KB; kb++) {
      if (kb + 1 < KB) {
        char* nb = ldsb + (cur ^ 1) * BUF;
        stageA(nb, kb + 1);
        stageB(nb + M_BLK * RS, kb + 1);
      }
      char* cb = ldsb + cur * BUF;
      compute(cb, cb + M_BLK * RS);
      __syncthreads();
      cur ^= 1;
    }
  } else {
    // BK == 64 in all VALU-staged modes
    for (int kb = 0; kb < KB; kb++) {
      __syncthreads();
      stageA(ldsb, kb);
      char* Bt = ldsb + M_BLK * RS;
      for (int g = AG + tid; g < AG + 512; g += 256) {
        const int h = g - AG, row = h >> 3, slot = h & 7;
        const int n = n0 + row;
        const int k = kb * 64 + slot * 8;
        short8 v = (short8)(short)0;
        if constexpr (MODE == 1) {
          const int d = k >> 8, ci = k & 255;
          const int wp = n % 7 + d - 1;
          if ((unsigned)wp <= 6u)
            v = *reinterpret_cast<const short8*>(in + (size_t)(n + d - 1) * 256 + ci);
        } else if constexpr (MODE == 2) {
          const int s2 = k >> 8, ci = k & 255;
          const int hh = (n % 49) / 7;
          if (hh + s2 >= 1)
            v = *reinterpret_cast<const short8*>(in + (size_t)(n + (s2 - 1) * 7) * 256 + ci);
        } else {
          // masked im2col: row = p in patch, gr = kb*8+slot, k = ci*64+ky*8+kx
          const int p = row;
          const int gr = kb * 8 + slot;
          const int ci = gr >> 3, ky = gr & 7;
          const int oy = p >> 3, ox = p & 7;
          const int y = oy * 8 + ky;
          const float* src = img + (((size_t)(pb * 3 + ci) * 256 + (size_t)(pR * 32 + y)) * 256
                                    + pC * 32 + ox * 8);
          float4 v0 = *reinterpret_cast<const float4*>(src);
          float4 v1 = *reinterpret_cast<const float4*>(src + 4);
          const bool rok = (y >= roff) && (y < roff + 60);
          float vals[8] = { v0.x, v0.y, v0.z, v0.w, v1.x, v1.y, v1.z, v1.w };
          const int x0 = ox * 8;
#pragma unroll
          for (int q = 0; q < 8; q++) {
            const int xx = x0 + q;
            const bool ok = rok && (xx >= coff) && (xx < coff + 60);
            v[q] = (short)f2bf(ok ? vals[q] : -1.0f);
          }
        }
        *reinterpret_cast<short8*>(Bt + row * RS + ((slot ^ (row & 7)) * 16)) = v;
      }
      __syncthreads();
      compute(ldsb, ldsb + M_BLK * RS);
    }
  }

#pragma unroll
  for (int mf = 0; mf < MF; mf++) {
    const int mb = m0 + w * (M_BLK / 4) + mf * 16 + lg * 4;
    float bv[4] = {0.f, 0.f, 0.f, 0.f};
    if constexpr (BIAS) {
      float4 t4 = *reinterpret_cast<const float4*>(bias + mb);
      bv[0] = t4.x; bv[1] = t4.y; bv[2] = t4.z; bv[3] = t4.w;
    }
#pragma unroll
    for (int nt = 0; nt < 4; nt++) {
      const size_t nn = (size_t)(n0 + nt * 16 + lr);
      const size_t off = nn * (size_t)M + mb + (size_t)z * ozs;
      float v[4];
#pragma unroll
      for (int r = 0; r < 4; r++) {
        v[r] = acc[mf][nt][r] + bv[r];
        if (SCALE) v[r] *= scale;
      }
      if (RESID) {
        short4v rv = *reinterpret_cast<const short4v*>(res + off);
#pragma unroll
        for (int r = 0; r < 4; r++) v[r] += bf2f((unsigned short)rv[r]);
      }
#pragma unroll
      for (int r = 0; r < 4; r++) if (RELU) v[r] = fmaxf(v[r], 0.f);
      if (OBF16) {
        short4v o;
#pragma unroll
        for (int r = 0; r < 4; r++) o[r] = (short)f2bf(v[r]);
        *reinterpret_cast<short4v*>(outb + off) = o;
      } else {
        float4 o; o.x = v[0]; o.y = v[1]; o.z = v[2]; o.w = v[3];
        *reinterpret_cast<float4*>(outf + off) = o;
      }
    }
  }
}

// ---------------- fused streaming logits + partial log-sum-exp ----------------
// Grid (63, 7). Block (bi, tz): 64 pred rows, targ tiles [tz*7, tz*7+7).
__global__ __launch_bounds__(256) void k_lse2(
    const unsigned short* __restrict__ predsb, const unsigned short* __restrict__ targ,
    float* __restrict__ pm, float* __restrict__ ps, float* __restrict__ zlab)
{
  __shared__ char At[8192];   // targ tile: 64 rows x 128B
  __shared__ char Bt[8192];   // preds tile: 64 rows x 128B
  __shared__ float redM[4][64], redS[4][64];
  const int tid = threadIdx.x;
  const int R0 = blockIdx.x * 64;
  const int tz = blockIdx.y;
  const int t0 = tz * 7;
  const int t1 = t0 + 7;
  int ip, base, cd7;
  if (R0 < 1792)      { ip = 0; base = 0;    cd7 = 28; }
  else if (R0 < 3136) { ip = 1; base = 1792; cd7 = 21; }
  else                { ip = 2; base = 3136; cd7 = 14; }
  const int lab7 = 7 * (ip + 3);
  const unsigned short* preds = predsb + (size_t)ip * 200704;
  const int w = tid >> 6, lane = tid & 63, lr = lane & 15, lg = lane >> 4;
  const int srow = lane >> 3, sslot = lane & 7;

#pragma unroll
  for (int c = 0; c < 2; c++) {
    const int rbase = w * 16 + c * 8;
    const int row = rbase + srow;
    const int rr = R0 - base + row;
    const int np = (rr / cd7) * 49 + (rr % cd7);
    gload16(preds + (size_t)np * 64 + ((sslot ^ (row & 7)) * 8), Bt + rbase * 128);
  }

  int labv[4];
#pragma unroll
  for (int nt = 0; nt < 4; nt++) {
    const int nc = R0 - base + nt * 16 + lr;
    labv[nt] = (nc / cd7) * 49 + (nc % cd7) + lab7;
  }
  float mrun[4] = {-1e30f, -1e30f, -1e30f, -1e30f};
  float srun[4] = {0.f, 0.f, 0.f, 0.f};

  for (int t = t0; t < t1; t++) {
#pragma unroll
    for (int c = 0; c < 2; c++) {
      const int rbase = w * 16 + c * 8;
      const int row = rbase + srow;
      gload16(targ + (size_t)(t * 64 + row) * 64 + ((sslot ^ (row & 7)) * 8),
              At + rbase * 128);
    }
    __syncthreads();
    f32x4 av[4];
#pragma unroll
    for (int nt = 0; nt < 4; nt++) av[nt] = (f32x4)0.f;
#pragma unroll
    for (int kk = 0; kk < 2; kk++) {
      const int gg = kk * 4 + lg;
      const int arow = w * 16 + lr;
      const short8 a = *reinterpret_cast<const short8*>(At + arow * 128 + ((gg ^ (arow & 7)) * 16));
#pragma unroll
      for (int nt = 0; nt < 4; nt++) {
        const int brow = nt * 16 + lr;
        const short8 b = *reinterpret_cast<const short8*>(Bt + brow * 128 + ((gg ^ (brow & 7)) * 16));
        av[nt] = mfma16(a, b, av[nt]);
      }
    }
    const int mg = t * 64 + w * 16 + lg * 4;
#pragma unroll
    for (int nt = 0; nt < 4; nt++) {
      float v0 = av[nt][0], v1 = av[nt][1], v2 = av[nt][2], v3 = av[nt][3];
      if (mg + 0 == labv[nt]) zlab[R0 + nt * 16 + lr] = v0;
      if (mg + 1 == labv[nt]) zlab[R0 + nt * 16 + lr] = v1;
      if (mg + 2 == labv[nt]) zlab[R0 + nt * 16 + lr] = v2;
      if (mg + 3 == labv[nt]) zlab[R0 + nt * 16 + lr] = v3;
      const float vm = fmaxf(fmaxf(v0, v1), fmaxf(v2, v3));
      const float nm = fmaxf(mrun[nt], vm);
      srun[nt] = srun[nt] * __expf(mrun[nt] - nm)
               + __expf(v0 - nm) + __expf(v1 - nm) + __expf(v2 - nm) + __expf(v3 - nm);
      mrun[nt] = nm;
    }
    __syncthreads();
  }
#pragma unroll
  for (int nt = 0; nt < 4; nt++) {
#pragma unroll
    for (int mk = 16; mk < 64; mk <<= 1) {
      const float om = __shfl_xor(mrun[nt], mk, 64);
      const float os = __shfl_xor(srun[nt], mk, 64);
      const float nm = fmaxf(mrun[nt], om);
      srun[nt] = srun[nt] * __expf(mrun[nt] - nm) + os * __expf(om - nm);
      mrun[nt] = nm;
    }
    if (lg == 0) { redM[w][nt * 16 + lr] = mrun[nt]; redS[w][nt * 16 + lr] = srun[nt]; }
  }
  __syncthreads();
  if (tid < 64) {
    float m = redM[0][tid], s = redS[0][tid];
#pragma unroll
    for (int wv = 1; wv < 4; wv++) {
      const float om = redM[wv][tid], os = redS[wv][tid];
      const float nm = fmaxf(m, om);
      s = s * __expf(m - nm) + os * __expf(om - nm);
      m = nm;
    }
    pm[(R0 + tid) * 7 + tz] = m;
    ps[(R0 + tid) * 7 + tz] = s;
  }
}

__global__ __launch_bounds__(256) void k_loss_final(
    const float* __restrict__ pm, const float* __restrict__ ps,
    const float* __restrict__ zlab, float* __restrict__ out)
{
  __shared__ float red[256];
  const int tid = threadIdx.x;
  float acc = 0.f;
  for (int i = tid; i < 4032; i += 256) {
    float m = pm[i * 7], s = ps[i * 7];
#pragma unroll
    for (int j = 1; j < 7; j++) {
      const float om = pm[i * 7 + j], os = ps[i * 7 + j];
      const float nm = fmaxf(m, om);
      s = s * __expf(m - nm) + os * __expf(om - nm);
      m = nm;
    }
    const float loss = (m + __logf(s)) - zlab[i];
    const float wgt = (i < 1792) ? (1.f / 1792.f) : ((i < 3136) ? (1.f / 1344.f) : (1.f / 896.f));
    acc += loss * wgt;
  }
  red[tid] = acc;
  for (int off = 128; off > 0; off >>= 1) {
    __syncthreads();
    if (tid < off) red[tid] += red[tid + off];
  }
  if (tid == 0) out[0] = red[0];
}

extern "C" void kernel_launch(void* const* d_in, const int* in_sizes, int n_in,
                              void* d_out, int out_size, void* d_ws, size_t ws_size,
                              hipStream_t stream)
{
  (void)in_sizes; (void)n_in; (void)out_size;
  const float* images = (const float*)d_in[0];
  const int*   rnd    = (const int*)d_in[1];
  const float* enc_w1 = (const float*)d_in[2];
  const float* enc_b1 = (const float*)d_in[3];
  const float* enc_w2 = (const float*)d_in[4];
  const float* enc_b2 = (const float*)d_in[5];
  const float* pc_w1  = (const float*)d_in[6];
  const float* pc_b1  = (const float*)d_in[7];
  const float* pc_w2  = (const float*)d_in[8];
  const float* pc_b2  = (const float*)d_in[9];
  const float* pc_w3  = (const float*)d_in[10];
  const float* pc_b3  = (const float*)d_in[11];
  const float* pc_w4  = (const float*)d_in[12];
  const float* pc_b4  = (const float*)d_in[13];
  const float* z2t_w  = (const float*)d_in[14];
  const float* z2t_b  = (const float*)d_in[15];
  const float* c2p_w  = (const float*)d_in[16];
  const float* c2p_b  = (const float*)d_in[17];
  float* out = (float*)d_out;
  char* ws = (char*)d_ws;

  // ws layout (bytes)
  unsigned short* w1b    = (unsigned short*)(ws + 0);          //    98,304
  unsigned short* w2b    = (unsigned short*)(ws + 98304);      // 1,048,576
  unsigned short* z2tb   = (unsigned short*)(ws + 1146880);    //   262,144
  unsigned short* c2pb   = (unsigned short*)(ws + 1409024);    //   786,432
  unsigned short* w2t    = (unsigned short*)(ws + 2195456);    // 1,966,080
  unsigned short* w3t    = (unsigned short*)(ws + 4161536);    // 1,310,720
  unsigned short* targ   = (unsigned short*)(ws + 5472256);    //   401,408
  unsigned short* predsb = (unsigned short*)(ws + 5873664);    // 1,204,224
  unsigned short* y1b    = (unsigned short*)(ws + 7094016);    // 1,605,632
  unsigned short* y2b    = (unsigned short*)(ws + 8699648);    // 1,605,632
  unsigned short* pcw1b  = (unsigned short*)(ws + 10305280);   // 5,242,880
  unsigned short* pcw4b  = (unsigned short*)(ws + 15548160);   // 5,242,880
  unsigned short* xbuf   = (unsigned short*)(ws + 20791040);   // 12,845,056 (end 33,636,096)
  // loss partials overlay the y1b region (dead after PixelCNN)
  float*          pm     = (float*)(ws + 7094016);             //   112,896
  float*          psum   = (float*)(ws + 7206912);             //   112,896
  float*          zlab   = (float*)(ws + 7319808);             //    16,128

  k_prep<<<12592, 256, 0, stream>>>(enc_w1, enc_w2, pc_w1, pc_w4, z2t_w, c2p_w,
                                    pc_w2, pc_w3,
                                    w1b, w2b, pcw1b, pcw4b, z2tb, c2pb, w2t, w3t);

  // ---- encoder: GEMM1 (masked im2col fused) -> H1, then pooled conv2 GEMM ----
  const size_t h1_off = 33636352;                    // 16B-aligned, after xbuf
  const size_t per_patch = 64 * 256 * 2;             // 32 KB of H1 per patch
  unsigned short* H1;
  int CH;
  if (ws_size > h1_off + 2 * per_patch) {
    size_t avail = (ws_size - h1_off) / per_patch;
    CH = (int)(avail > 3136 ? 3136 : avail) & ~1;
    H1 = (unsigned short*)(ws + h1_off);
  } else {
    // fallback: reuse dead y1b/y2b region (contiguous 3.2 MB -> 98 patches)
    H1 = y1b;
    CH = 98;
  }
  for (int base = 0; base < 3136; base += CH) {
    const int c = (3136 - base) < CH ? (3136 - base) : CH;
    k_gemm<256, 64, 4, true, true, false, false, true><<<dim3(1, c), 256, 0, stream>>>(
        nullptr, w1b, enc_b1, nullptr, H1, nullptr, 256, 192, 0, base, 1.f,
        0, 0, 0, images, rnd);
    k_enc2<<<16 * (c / 2), 256, 0, stream>>>(H1, w2b, enc_b2, xbuf, base);
  }

  k_out2<<<dim3(8, 64), 256, 0, stream>>>(xbuf, out);
  k_gemm<64, 128, 0, true, false, false, false, true><<<dim3(1, 49), 256, 0, stream>>>(
      xbuf, z2tb, z2t_b, nullptr, targ, nullptr, 64, 2048, 2048, 0, 1.f, 0, 0, 0,
      nullptr, nullptr);

  // PixelCNN: 5 residual blocks (all MFMA GEMMs; y3 reuses y1b)
  for (int k = 0; k < 5; k++) {
    k_gemm<64, 128, 0, true, true, false, false, true><<<dim3(4, 49), 256, 0, stream>>>(
        xbuf, pcw1b + (size_t)k * 524288, pc_b1 + k * 256, nullptr, y1b, nullptr,
        256, 2048, 2048, 0, 1.f, 0, 0, 0, nullptr, nullptr);
    k_gemm<64, 64, 1, true, true, false, false, true><<<dim3(4, 49), 256, 0, stream>>>(
        y1b, w2t + (size_t)k * 196608, pc_b2 + k * 256, nullptr, y2b, nullptr,
        256, 768, 256, 0, 1.f, 0, 0, 0, nullptr, nullptr);
    k_gemm<64, 64, 2, true, true, false, false, true><<<dim3(4, 49), 256, 0, stream>>>(
        y2b, w3t + (size_t)k * 131072, pc_b3 + k * 256, nullptr, y1b, nullptr,
        256, 512, 256, 0, 1.f, 0, 0, 0, nullptr, nullptr);
    k_gemm<128, 64, 0, true, true, true, false, true><<<dim3(16, 49), 256, 0, stream>>>(
        y1b, pcw4b + (size_t)k * 524288, pc_b4 + k * 2048, nullptr, xbuf, xbuf,
        2048, 256, 256, 0, 1.f, 0, 0, 0, nullptr, nullptr);
  }

  // all 3 preds in one z-batched launch (xbuf still live)
  k_gemm<64, 128, 0, true, false, false, true, true><<<dim3(1, 49, 3), 256, 0, stream>>>(
      xbuf, c2pb, c2p_b, nullptr, predsb, nullptr, 64, 2048, 2048, 0, 0.1f,
      131072, 64, 200704, nullptr, nullptr);

  // fused streaming logits+LSE, t-split 7-way (y1b region is dead by now)
  k_lse2<<<dim3(63, 7), 256, 0, stream>>>(predsb, targ, pm, psum, zlab);
  k_loss_final<<<1, 256, 0, stream>>>(pm, psum, zlab, out);
}

// Round 14
// 588.499 us; speedup vs baseline: 1.1154x; 1.0811x over previous
//
#include <hip/hip_runtime.h>
#include <hip/hip_bf16.h>
#include <cstdint>
#include <cstddef>

typedef __attribute__((ext_vector_type(8))) short short8;
typedef __attribute__((ext_vector_type(4))) short short4v;
typedef __attribute__((ext_vector_type(4))) float f32x4;

__device__ __forceinline__ float bf2f(unsigned short u) {
  union { unsigned int i; float f; } v; v.i = ((unsigned int)u) << 16; return v.f;
}
__device__ __forceinline__ unsigned short f2bf(float f) {
  union { float f; unsigned int i; } v; v.f = f;
  unsigned int x = v.i;
  return (unsigned short)((x + 0x7fffu + ((x >> 16) & 1u)) >> 16);
}
__device__ __forceinline__ f32x4 mfma16(short8 a, short8 b, f32x4 c) {
  return __builtin_amdgcn_mfma_f32_16x16x32_bf16(a, b, c, 0, 0, 0);
}
// async global->LDS, 16B/lane. dst must be wave-uniform; HW writes dst + lane*16.
__device__ __forceinline__ void gload16(const void* src, void* dst) {
  __builtin_amdgcn_global_load_lds(
      (const __attribute__((address_space(1))) unsigned int*)src,
      (__attribute__((address_space(3))) unsigned int*)dst, 16, 0, 0);
}

// ---------------- fused weight prep: fp32->bf16 (+ transposes for 1x3 / 2x1 convs) -------
__device__ __forceinline__ void cvt4(const float* __restrict__ src,
                                     unsigned short* __restrict__ dst, int i) {
  float4 v = reinterpret_cast<const float4*>(src)[i];
  short4v o;
  o[0] = (short)f2bf(v.x); o[1] = (short)f2bf(v.y);
  o[2] = (short)f2bf(v.z); o[3] = (short)f2bf(v.w);
  reinterpret_cast<short4v*>(dst)[i] = o;
}

__global__ __launch_bounds__(256) void k_prep(
    const float* __restrict__ enc_w1, const float* __restrict__ enc_w2,
    const float* __restrict__ pc_w1, const float* __restrict__ pc_w4,
    const float* __restrict__ z2t_w, const float* __restrict__ c2p_w,
    const float* __restrict__ pc_w2, const float* __restrict__ pc_w3,
    unsigned short* __restrict__ w1b, unsigned short* __restrict__ w2b,
    unsigned short* __restrict__ pcw1b, unsigned short* __restrict__ pcw4b,
    unsigned short* __restrict__ z2tb, unsigned short* __restrict__ c2pb,
    unsigned short* __restrict__ w2t, unsigned short* __restrict__ w3t,
    unsigned short* __restrict__ zbuf)
{
  const int b = blockIdx.x, tid = threadIdx.x;
  if (b == 0 && tid < 32) zbuf[tid] = 0;   // zero-fill source for gload16 gather modes
  if (b < 48)        cvt4(enc_w1, w1b,   b * 256 + tid);
  else if (b < 560)  cvt4(enc_w2, w2b,   (b - 48) * 256 + tid);
  else if (b < 3120) cvt4(pc_w1,  pcw1b, (b - 560) * 256 + tid);
  else if (b < 5680) cvt4(pc_w4,  pcw4b, (b - 3120) * 256 + tid);
  else if (b < 5808) cvt4(z2t_w,  z2tb,  (b - 5680) * 256 + tid);
  else if (b < 6192) cvt4(c2p_w,  c2pb,  (b - 5808) * 256 + tid);
  else if (b < 10032) {
    // pc_w2 [5][co][ci][1][3] -> w2t [5][co][d*256+ci]
    const int e = (b - 6192) * 256 + tid;
    const int k5 = e / 196608, r = e % 196608;
    const int co = r / 768, kk = r % 768, d = kk >> 8, ci = kk & 255;
    w2t[e] = f2bf(pc_w2[((size_t)(k5 * 256 + co) * 256 + ci) * 3 + d]);
  } else {
    // pc_w3 [5][co][ci][2][1] -> w3t [5][co][s*256+ci]
    const int e = (b - 10032) * 256 + tid;
    const int k5 = e / 131072, r = e % 131072;
    const int co = r >> 9, kk = r & 511, s = kk >> 8, ci = kk & 255;
    w3t[e] = f2bf(pc_w3[((size_t)(k5 * 256 + co) * 256 + ci) * 2 + s]);
  }
}

// ---------------- conv2 + relu + mean-pool GEMM (single-buffer, proven 282us) ------------
// FROZEN. dbuf@64KB (r6), 512-thread/48KB (r8), A-direct (r10) all regressed.
__global__ __launch_bounds__(256) void k_enc2(
    const unsigned short* __restrict__ H1, const unsigned short* __restrict__ w2b,
    const float* __restrict__ b2, unsigned short* __restrict__ xout, int gbase)
{
  __shared__ char lds[32768];
  char* At = lds;            // 128 co rows x 8 granules (linear)
  char* Bt = lds + 16384;    // 128 pos rows x 8 granules (linear)
  const int tid = threadIdx.x;
  const int nwg = gridDim.x;
  int bid = blockIdx.x;
  int l = bid;
  if ((nwg & 7) == 0) { const int cpx = nwg >> 3; l = (bid & 7) * cpx + (bid >> 3); }
  const int m0 = (l & 15) * 128;
  const int by = l >> 4;
  const int w = tid >> 6, lane = tid & 63, lr = lane & 15, lg = lane >> 4;
  const int wm = w & 1, wn = w >> 1;
  const int srow = lane >> 3, sslot = lane & 7;
  f32x4 acc[4][4];
  for (int i = 0; i < 4; i++) for (int j = 0; j < 4; j++) acc[i][j] = (f32x4)0.f;
  for (int kb = 0; kb < 4; kb++) {
    __syncthreads();
#pragma unroll
    for (int c = 0; c < 4; c++) {
      const int rbase = w * 32 + c * 8;
      const int row = rbase + srow;
      gload16(w2b + (size_t)(m0 + row) * 256 + kb * 64 + ((sslot ^ (row & 7)) * 8),
              At + rbase * 128);
    }
#pragma unroll
    for (int c = 0; c < 4; c++) {
      const int rbase = w * 32 + c * 8;
      const int row = rbase + srow;
      gload16(H1 + (size_t)(by * 128 + row) * 256 + kb * 64 + ((sslot ^ (row & 7)) * 8),
              Bt + rbase * 128);
    }
    __syncthreads();
#pragma unroll
    for (int kk = 0; kk < 2; kk++) {
      const int gg = kk * 4 + lg;
      short8 bb[4];
#pragma unroll
      for (int nt = 0; nt < 4; nt++) {
        const int row = wn * 64 + nt * 16 + lr;
        bb[nt] = *reinterpret_cast<const short8*>(Bt + row * 128 + ((gg ^ (row & 7)) * 16));
      }
#pragma unroll
      for (int cot = 0; cot < 4; cot++) {
        const int row = wm * 64 + cot * 16 + lr;
        const short8 a = *reinterpret_cast<const short8*>(At + row * 128 + ((gg ^ (row & 7)) * 16));
#pragma unroll
        for (int nt = 0; nt < 4; nt++)
          acc[cot][nt] = mfma16(a, bb[nt], acc[cot][nt]);
      }
    }
  }
  // epilogue: relu(+b2), pool over this wave's 64 positions (= its patch)
  const int n = gbase + by * 2 + wn;
#pragma unroll
  for (int cot = 0; cot < 4; cot++) {
    const int cob = m0 + wm * 64 + cot * 16 + lg * 4;
    float4 bi = *reinterpret_cast<const float4*>(b2 + cob);
    const float bv[4] = { bi.x, bi.y, bi.z, bi.w };
    float s[4] = { 0.f, 0.f, 0.f, 0.f };
#pragma unroll
    for (int nt = 0; nt < 4; nt++)
#pragma unroll
      for (int r = 0; r < 4; r++)
        s[r] += fmaxf(acc[cot][nt][r] + bv[r], 0.f);
#pragma unroll
    for (int r = 0; r < 4; r++)
#pragma unroll
      for (int mk = 1; mk < 16; mk <<= 1)
        s[r] += __shfl_xor(s[r], mk, 64);
    if (lr == 0) {
      short4v o;
#pragma unroll
      for (int r = 0; r < 4; r++) o[r] = (short)f2bf(s[r] * (1.f / 64.f));
      *reinterpret_cast<short4v*>(xout + (size_t)n * 2048 + cob) = o;
    }
  }
}

// ---------------- latents mean over 49 patches ----------------
__global__ __launch_bounds__(256) void k_out2(const unsigned short* __restrict__ x,
                                              float* __restrict__ out) {
  const int ch = blockIdx.x * 256 + threadIdx.x;
  const int b = blockIdx.y;
  float s = 0.f;
  for (int p = 0; p < 49; p++) s += bf2f(x[(size_t)(b * 49 + p) * 2048 + ch]);
  out[1 + b * 2048 + ch] = s * (1.f / 49.f);
}

// ---------------- generic bf16 MFMA GEMM with gather modes ----------------
// MODE 0: B row n = in + n*bstride            (gload-lds, dbuf 2-phase, BK 64/128)
// MODE 1: 1x3 width conv gather (tap d const per kb; invalid rows read zbuf)  — gload dbuf
// MODE 2: 2x1 height conv gather (tap s const per kb; invalid rows read zbuf) — gload dbuf
// MODE 4: masked im2col from images (VALU staged, BK=64)
template<int M_BLK, int BK, int MODE, bool BIAS, bool RELU, bool RESID, bool SCALE, bool OBF16>
__global__ __launch_bounds__(256) void k_gemm(
    const unsigned short* __restrict__ in, const unsigned short* __restrict__ W,
    const float* __restrict__ bias, float* __restrict__ outf,
    unsigned short* __restrict__ outb, const unsigned short* __restrict__ res,
    int M, int K, int bstride, int aux, float scale,
    int wzs, int bzs, int ozs,
    const float* __restrict__ img, const int* __restrict__ rndp,
    const unsigned short* __restrict__ zbuf)
{
  constexpr int MF = M_BLK / 64;
  constexpr int GPR = BK / 8;          // 16B granules per row
  constexpr int ROWS = 64 / GPR;       // rows per wave gload16
  constexpr int RS = BK * 2;           // row stride bytes
  constexpr int CHA = (M_BLK / 4) / ROWS;
  constexpr int CHB = 16 / ROWS;
  constexpr int AG = M_BLK * 8;        // A granules per K-block (BK=64 VALU path)
  constexpr bool DBUF = (MODE <= 2);
  constexpr int BUF = (M_BLK + 64) * RS;
  __shared__ char ldsb[(DBUF ? 2 : 1) * BUF];
  const int tid = threadIdx.x;
  const int z = blockIdx.z;
  W += (size_t)z * wzs;
  if (BIAS) bias += (size_t)z * bzs;
  const int m0 = blockIdx.x * M_BLK;
  const int n0 = blockIdx.y * 64;
  const int w = tid >> 6, lane = tid & 63, lr = lane & 15, lg = lane >> 4;
  const int srow = lane / GPR, sslot = lane % GPR;
  int pb = 0, pR = 0, pC = 0, roff = 0, coff = 0;
  if constexpr (MODE == 4) {
    const int pn = aux + blockIdx.y;
    pb = pn / 49; const int prc = pn % 49; pR = prc / 7; pC = prc % 7;
    const int rv = rndp[pn];
    roff = rv >> 2; coff = rv & 3;
  }
  f32x4 acc[MF][4];
  for (int mf = 0; mf < MF; mf++) for (int nt = 0; nt < 4; nt++) acc[mf][nt] = (f32x4)0.f;
  const int KB = K / BK;

  auto stageA = [&](char* At, int kb) {
#pragma unroll
    for (int c = 0; c < CHA; c++) {
      const int rbase = w * (M_BLK / 4) + c * ROWS;
      const int row = rbase + srow;
      gload16(W + (size_t)(m0 + row) * K + kb * BK + ((sslot ^ (row & 7)) * 8),
              At + rbase * RS);
    }
  };
  auto compute = [&](const char* At, const char* Bt) {
#pragma unroll
    for (int kk = 0; kk < BK / 32; kk++) {
      short8 a[MF], bb[4];
      const int gg = kk * 4 + lg;
#pragma unroll
      for (int mf = 0; mf < MF; mf++) {
        const int row = w * (M_BLK / 4) + mf * 16 + lr;
        a[mf] = *reinterpret_cast<const short8*>(At + row * RS + ((gg ^ (row & 7)) * 16));
      }
#pragma unroll
      for (int nt = 0; nt < 4; nt++) {
        const int row = nt * 16 + lr;
        bb[nt] = *reinterpret_cast<const short8*>(Bt + row * RS + ((gg ^ (row & 7)) * 16));
      }
#pragma unroll
      for (int mf = 0; mf < MF; mf++)
#pragma unroll
        for (int nt = 0; nt < 4; nt++)
          acc[mf][nt] = mfma16(a[mf], bb[nt], acc[mf][nt]);
    }
  };

  if constexpr (DBUF) {
    auto stageB = [&](char* Bt, int kb) {
#pragma unroll
      for (int c = 0; c < CHB; c++) {
        const int rbase = w * 16 + c * ROWS;
        const int row = rbase + srow;
        const int n = n0 + row;
        const unsigned short* src;
        if constexpr (MODE == 0) {
          src = in + (size_t)n * bstride + kb * BK + ((sslot ^ (row & 7)) * 8);
        } else if constexpr (MODE == 1) {
          const int d = (kb * BK) >> 8;          // tap, constant within kb (BK=64)
          const int ci0 = (kb * BK) & 255;
          const int wp = n % 7 + d - 1;
          src = ((unsigned)wp <= 6u)
              ? in + (size_t)(n + d - 1) * 256 + ci0 + ((sslot ^ (row & 7)) * 8)
              : zbuf;
        } else {                                  // MODE 2
          const int s2 = (kb * BK) >> 8;
          const int ci0 = (kb * BK) & 255;
          const int hh = (n % 49) / 7;
          src = (hh + s2 >= 1)
              ? in + (size_t)(n + (s2 - 1) * 7) * 256 + ci0 + ((sslot ^ (row & 7)) * 8)
              : zbuf;
        }
        gload16(src, Bt + rbase * RS);
      }
    };
    stageA(ldsb, 0);
    stageB(ldsb + M_BLK * RS, 0);
    __syncthreads();
    int cur = 0;
    for (int kb = 0; kb < KB; kb++) {
      if (kb + 1 < KB) {
        char* nb = ldsb + (cur ^ 1) * BUF;
        stageA(nb, kb + 1);
        stageB(nb + M_BLK * RS, kb + 1);
      }
      char* cb = ldsb + cur * BUF;
      compute(cb, cb + M_BLK * RS);
      __syncthreads();
      cur ^= 1;
    }
  } else {
    // BK == 64 (MODE 4)
    for (int kb = 0; kb < KB; kb++) {
      __syncthreads();
      stageA(ldsb, kb);
      char* Bt = ldsb + M_BLK * RS;
      for (int g = AG + tid; g < AG + 512; g += 256) {
        const int h = g - AG, row = h >> 3, slot = h & 7;
        short8 v = (short8)(short)0;
        {
          // masked im2col: row = p in patch, gr = kb*8+slot, k = ci*64+ky*8+kx
          const int p = row;
          const int gr = kb * 8 + slot;
          const int ci = gr >> 3, ky = gr & 7;
          const int oy = p >> 3, ox = p & 7;
          const int y = oy * 8 + ky;
          const float* src = img + (((size_t)(pb * 3 + ci) * 256 + (size_t)(pR * 32 + y)) * 256
                                    + pC * 32 + ox * 8);
          float4 v0 = *reinterpret_cast<const float4*>(src);
          float4 v1 = *reinterpret_cast<const float4*>(src + 4);
          const bool rok = (y >= roff) && (y < roff + 60);
          float vals[8] = { v0.x, v0.y, v0.z, v0.w, v1.x, v1.y, v1.z, v1.w };
          const int x0 = ox * 8;
#pragma unroll
          for (int q = 0; q < 8; q++) {
            const int xx = x0 + q;
            const bool ok = rok && (xx >= coff) && (xx < coff + 60);
            v[q] = (short)f2bf(ok ? vals[q] : -1.0f);
          }
        }
        *reinterpret_cast<short8*>(Bt + row * RS + ((slot ^ (row & 7)) * 16)) = v;
      }
      __syncthreads();
      compute(ldsb, ldsb + M_BLK * RS);
    }
  }

#pragma unroll
  for (int mf = 0; mf < MF; mf++) {
    const int mb = m0 + w * (M_BLK / 4) + mf * 16 + lg * 4;
    float bv[4] = {0.f, 0.f, 0.f, 0.f};
    if constexpr (BIAS) {
      float4 t4 = *reinterpret_cast<const float4*>(bias + mb);
      bv[0] = t4.x; bv[1] = t4.y; bv[2] = t4.z; bv[3] = t4.w;
    }
#pragma unroll
    for (int nt = 0; nt < 4; nt++) {
      const size_t nn = (size_t)(n0 + nt * 16 + lr);
      const size_t off = nn * (size_t)M + mb + (size_t)z * ozs;
      float v[4];
#pragma unroll
      for (int r = 0; r < 4; r++) {
        v[r] = acc[mf][nt][r] + bv[r];
        if (SCALE) v[r] *= scale;
      }
      if (RESID) {
        short4v rv = *reinterpret_cast<const short4v*>(res + off);
#pragma unroll
        for (int r = 0; r < 4; r++) v[r] += bf2f((unsigned short)rv[r]);
      }
#pragma unroll
      for (int r = 0; r < 4; r++) if (RELU) v[r] = fmaxf(v[r], 0.f);
      if (OBF16) {
        short4v o;
#pragma unroll
        for (int r = 0; r < 4; r++) o[r] = (short)f2bf(v[r]);
        *reinterpret_cast<short4v*>(outb + off) = o;
      } else {
        float4 o; o.x = v[0]; o.y = v[1]; o.z = v[2]; o.w = v[3];
        *reinterpret_cast<float4*>(outf + off) = o;
      }
    }
  }
}

// ---------------- fused streaming logits + partial log-sum-exp ----------------
// Grid (63, 7). Block (bi, tz): 64 pred rows, targ tiles [tz*7, tz*7+7).
__global__ __launch_bounds__(256) void k_lse2(
    const unsigned short* __restrict__ predsb, const unsigned short* __restrict__ targ,
    float* __restrict__ pm, float* __restrict__ ps, float* __restrict__ zlab)
{
  __shared__ char At[8192];   // targ tile: 64 rows x 128B
  __shared__ char Bt[8192];   // preds tile: 64 rows x 128B
  __shared__ float redM[4][64], redS[4][64];
  const int tid = threadIdx.x;
  const int R0 = blockIdx.x * 64;
  const int tz = blockIdx.y;
  const int t0 = tz * 7;
  const int t1 = t0 + 7;
  int ip, base, cd7;
  if (R0 < 1792)      { ip = 0; base = 0;    cd7 = 28; }
  else if (R0 < 3136) { ip = 1; base = 1792; cd7 = 21; }
  else                { ip = 2; base = 3136; cd7 = 14; }
  const int lab7 = 7 * (ip + 3);
  const unsigned short* preds = predsb + (size_t)ip * 200704;
  const int w = tid >> 6, lane = tid & 63, lr = lane & 15, lg = lane >> 4;
  const int srow = lane >> 3, sslot = lane & 7;

#pragma unroll
  for (int c = 0; c < 2; c++) {
    const int rbase = w * 16 + c * 8;
    const int row = rbase + srow;
    const int rr = R0 - base + row;
    const int np = (rr / cd7) * 49 + (rr % cd7);
    gload16(preds + (size_t)np * 64 + ((sslot ^ (row & 7)) * 8), Bt + rbase * 128);
  }

  int labv[4];
#pragma unroll
  for (int nt = 0; nt < 4; nt++) {
    const int nc = R0 - base + nt * 16 + lr;
    labv[nt] = (nc / cd7) * 49 + (nc % cd7) + lab7;
  }
  float mrun[4] = {-1e30f, -1e30f, -1e30f, -1e30f};
  float srun[4] = {0.f, 0.f, 0.f, 0.f};

  for (int t = t0; t < t1; t++) {
#pragma unroll
    for (int c = 0; c < 2; c++) {
      const int rbase = w * 16 + c * 8;
      const int row = rbase + srow;
      gload16(targ + (size_t)(t * 64 + row) * 64 + ((sslot ^ (row & 7)) * 8),
              At + rbase * 128);
    }
    __syncthreads();
    f32x4 av[4];
#pragma unroll
    for (int nt = 0; nt < 4; nt++) av[nt] = (f32x4)0.f;
#pragma unroll
    for (int kk = 0; kk < 2; kk++) {
      const int gg = kk * 4 + lg;
      const int arow = w * 16 + lr;
      const short8 a = *reinterpret_cast<const short8*>(At + arow * 128 + ((gg ^ (arow & 7)) * 16));
#pragma unroll
      for (int nt = 0; nt < 4; nt++) {
        const int brow = nt * 16 + lr;
        const short8 b = *reinterpret_cast<const short8*>(Bt + brow * 128 + ((gg ^ (brow & 7)) * 16));
        av[nt] = mfma16(a, b, av[nt]);
      }
    }
    const int mg = t * 64 + w * 16 + lg * 4;
#pragma unroll
    for (int nt = 0; nt < 4; nt++) {
      float v0 = av[nt][0], v1 = av[nt][1], v2 = av[nt][2], v3 = av[nt][3];
      if (mg + 0 == labv[nt]) zlab[R0 + nt * 16 + lr] = v0;
      if (mg + 1 == labv[nt]) zlab[R0 + nt * 16 + lr] = v1;
      if (mg + 2 == labv[nt]) zlab[R0 + nt * 16 + lr] = v2;
      if (mg + 3 == labv[nt]) zlab[R0 + nt * 16 + lr] = v3;
      const float vm = fmaxf(fmaxf(v0, v1), fmaxf(v2, v3));
      const float nm = fmaxf(mrun[nt], vm);
      srun[nt] = srun[nt] * __expf(mrun[nt] - nm)
               + __expf(v0 - nm) + __expf(v1 - nm) + __expf(v2 - nm) + __expf(v3 - nm);
      mrun[nt] = nm;
    }
    __syncthreads();
  }
#pragma unroll
  for (int nt = 0; nt < 4; nt++) {
#pragma unroll
    for (int mk = 16; mk < 64; mk <<= 1) {
      const float om = __shfl_xor(mrun[nt], mk, 64);
      const float os = __shfl_xor(srun[nt], mk, 64);
      const float nm = fmaxf(mrun[nt], om);
      srun[nt] = srun[nt] * __expf(mrun[nt] - nm) + os * __expf(om - nm);
      mrun[nt] = nm;
    }
    if (lg == 0) { redM[w][nt * 16 + lr] = mrun[nt]; redS[w][nt * 16 + lr] = srun[nt]; }
  }
  __syncthreads();
  if (tid < 64) {
    float m = redM[0][tid], s = redS[0][tid];
#pragma unroll
    for (int wv = 1; wv < 4; wv++) {
      const float om = redM[wv][tid], os = redS[wv][tid];
      const float nm = fmaxf(m, om);
      s = s * __expf(m - nm) + os * __expf(om - nm);
      m = nm;
    }
    pm[(R0 + tid) * 7 + tz] = m;
    ps[(R0 + tid) * 7 + tz] = s;
  }
}

__global__ __launch_bounds__(256) void k_loss_final(
    const float* __restrict__ pm, const float* __restrict__ ps,
    const float* __restrict__ zlab, float* __restrict__ out)
{
  __shared__ float red[256];
  const int tid = threadIdx.x;
  float acc = 0.f;
  for (int i = tid; i < 4032; i += 256) {
    float m = pm[i * 7], s = ps[i * 7];
#pragma unroll
    for (int j = 1; j < 7; j++) {
      const float om = pm[i * 7 + j], os = ps[i * 7 + j];
      const float nm = fmaxf(m, om);
      s = s * __expf(m - nm) + os * __expf(om - nm);
      m = nm;
    }
    const float loss = (m + __logf(s)) - zlab[i];
    const float wgt = (i < 1792) ? (1.f / 1792.f) : ((i < 3136) ? (1.f / 1344.f) : (1.f / 896.f));
    acc += loss * wgt;
  }
  red[tid] = acc;
  for (int off = 128; off > 0; off >>= 1) {
    __syncthreads();
    if (tid < off) red[tid] += red[tid + off];
  }
  if (tid == 0) out[0] = red[0];
}

extern "C" void kernel_launch(void* const* d_in, const int* in_sizes, int n_in,
                              void* d_out, int out_size, void* d_ws, size_t ws_size,
                              hipStream_t stream)
{
  (void)in_sizes; (void)n_in; (void)out_size;
  const float* images = (const float*)d_in[0];
  const int*   rnd    = (const int*)d_in[1];
  const float* enc_w1 = (const float*)d_in[2];
  const float* enc_b1 = (const float*)d_in[3];
  const float* enc_w2 = (const float*)d_in[4];
  const float* enc_b2 = (const float*)d_in[5];
  const float* pc_w1  = (const float*)d_in[6];
  const float* pc_b1  = (const float*)d_in[7];
  const float* pc_w2  = (const float*)d_in[8];
  const float* pc_b2  = (const float*)d_in[9];
  const float* pc_w3  = (const float*)d_in[10];
  const float* pc_b3  = (const float*)d_in[11];
  const float* pc_w4  = (const float*)d_in[12];
  const float* pc_b4  = (const float*)d_in[13];
  const float* z2t_w  = (const float*)d_in[14];
  const float* z2t_b  = (const float*)d_in[15];
  const float* c2p_w  = (const float*)d_in[16];
  const float* c2p_b  = (const float*)d_in[17];
  float* out = (float*)d_out;
  char* ws = (char*)d_ws;

  // ws layout (bytes)
  unsigned short* w1b    = (unsigned short*)(ws + 0);          //    98,304
  unsigned short* w2b    = (unsigned short*)(ws + 98304);      // 1,048,576
  unsigned short* z2tb   = (unsigned short*)(ws + 1146880);    //   262,144
  unsigned short* c2pb   = (unsigned short*)(ws + 1409024);    //   786,432
  unsigned short* w2t    = (unsigned short*)(ws + 2195456);    // 1,966,080
  unsigned short* w3t    = (unsigned short*)(ws + 4161536);    // 1,310,720
  unsigned short* targ   = (unsigned short*)(ws + 5472256);    //   401,408
  unsigned short* predsb = (unsigned short*)(ws + 5873664);    // 1,204,224
  unsigned short* zbuf   = (unsigned short*)(ws + 7077888);    //        64 (ex-lossr gap)
  unsigned short* y1b    = (unsigned short*)(ws + 7094016);    // 1,605,632
  unsigned short* y2b    = (unsigned short*)(ws + 8699648);    // 1,605,632
  unsigned short* pcw1b  = (unsigned short*)(ws + 10305280);   // 5,242,880
  unsigned short* pcw4b  = (unsigned short*)(ws + 15548160);   // 5,242,880
  unsigned short* xbuf   = (unsigned short*)(ws + 20791040);   // 12,845,056 (end 33,636,096)
  // loss partials overlay the y1b region (dead after PixelCNN)
  float*          pm     = (float*)(ws + 7094016);             //   112,896
  float*          psum   = (float*)(ws + 7206912);             //   112,896
  float*          zlab   = (float*)(ws + 7319808);             //    16,128

  k_prep<<<12592, 256, 0, stream>>>(enc_w1, enc_w2, pc_w1, pc_w4, z2t_w, c2p_w,
                                    pc_w2, pc_w3,
                                    w1b, w2b, pcw1b, pcw4b, z2tb, c2pb, w2t, w3t, zbuf);

  // ---- encoder: GEMM1 (masked im2col fused) -> H1, then pooled conv2 GEMM ----
  const size_t h1_off = 33636352;                    // 16B-aligned, after xbuf
  const size_t per_patch = 64 * 256 * 2;             // 32 KB of H1 per patch
  unsigned short* H1;
  int CH;
  if (ws_size > h1_off + 2 * per_patch) {
    size_t avail = (ws_size - h1_off) / per_patch;
    CH = (int)(avail > 3136 ? 3136 : avail) & ~1;
    H1 = (unsigned short*)(ws + h1_off);
  } else {
    // fallback: reuse dead y1b/y2b region (contiguous 3.2 MB -> 98 patches)
    H1 = y1b;
    CH = 98;
  }
  for (int base = 0; base < 3136; base += CH) {
    const int c = (3136 - base) < CH ? (3136 - base) : CH;
    k_gemm<256, 64, 4, true, true, false, false, true><<<dim3(1, c), 256, 0, stream>>>(
        nullptr, w1b, enc_b1, nullptr, H1, nullptr, 256, 192, 0, base, 1.f,
        0, 0, 0, images, rnd, nullptr);
    k_enc2<<<16 * (c / 2), 256, 0, stream>>>(H1, w2b, enc_b2, xbuf, base);
  }

  k_out2<<<dim3(8, 64), 256, 0, stream>>>(xbuf, out);
  k_gemm<64, 128, 0, true, false, false, false, true><<<dim3(1, 49), 256, 0, stream>>>(
      xbuf, z2tb, z2t_b, nullptr, targ, nullptr, 64, 2048, 2048, 0, 1.f, 0, 0, 0,
      nullptr, nullptr, nullptr);

  // PixelCNN: 5 residual blocks (all MFMA GEMMs; y3 reuses y1b)
  for (int k = 0; k < 5; k++) {
    k_gemm<64, 128, 0, true, true, false, false, true><<<dim3(4, 49), 256, 0, stream>>>(
        xbuf, pcw1b + (size_t)k * 524288, pc_b1 + k * 256, nullptr, y1b, nullptr,
        256, 2048, 2048, 0, 1.f, 0, 0, 0, nullptr, nullptr, nullptr);
    k_gemm<64, 64, 1, true, true, false, false, true><<<dim3(4, 49), 256, 0, stream>>>(
        y1b, w2t + (size_t)k * 196608, pc_b2 + k * 256, nullptr, y2b, nullptr,
        256, 768, 256, 0, 1.f, 0, 0, 0, nullptr, nullptr, zbuf);
    k_gemm<64, 64, 2, true, true, false, false, true><<<dim3(4, 49), 256, 0, stream>>>(
        y2b, w3t + (size_t)k * 131072, pc_b3 + k * 256, nullptr, y1b, nullptr,
        256, 512, 256, 0, 1.f, 0, 0, 0, nullptr, nullptr, zbuf);
    k_gemm<128, 64, 0, true, true, true, false, true><<<dim3(16, 49), 256, 0, stream>>>(
        y1b, pcw4b + (size_t)k * 524288, pc_b4 + k * 2048, nullptr, xbuf, xbuf,
        2048, 256, 256, 0, 1.f, 0, 0, 0, nullptr, nullptr, nullptr);
  }

  // all 3 preds in one z-batched launch (xbuf still live)
  k_gemm<64, 128, 0, true, false, false, true, true><<<dim3(1, 49, 3), 256, 0, stream>>>(
      xbuf, c2pb, c2p_b, nullptr, predsb, nullptr, 64, 2048, 2048, 0, 0.1f,
      131072, 64, 200704, nullptr, nullptr, nullptr);

  // fused streaming logits+LSE, t-split 7-way (y1b region is dead by now)
  k_lse2<<<dim3(63, 7), 256, 0, stream>>>(predsb, targ, pm, psum, zlab);
  k_loss_final<<<1, 256, 0, stream>>>(pm, psum, zlab, out);
}